// Round 15
// baseline (96.921 us; speedup 1.0000x reference)
//
#include <hip/hip_runtime.h>

#define B_ 4
#define T_ 4096
#define E_ 512
#define A_ 64
#define SQSCALE 0.1803368801111204f   // log2(e)/8 : folds softmax scale + exp->exp2

typedef __attribute__((ext_vector_type(8)))  short bf16x8;
typedef __attribute__((ext_vector_type(8)))  unsigned short ushort8;
typedef __attribute__((ext_vector_type(4)))  unsigned int   u32x4;
typedef __attribute__((ext_vector_type(4)))  float f32x4;
typedef __attribute__((ext_vector_type(16))) float f32x16;

__device__ __forceinline__ unsigned short f2bf(float x) {
    union { float f; unsigned int u; } v; v.f = x;
    unsigned int r = v.u + 0x7fffu + ((v.u >> 16) & 1u);
    return (unsigned short)(r >> 16);
}
__device__ __forceinline__ unsigned cvtpk(float a, float b) {
    unsigned r;
    asm("v_cvt_pk_bf16_f32 %0, %1, %2" : "=v"(r) : "v"(a), "v"(b));
    return r;
}
// v_permlane32_swap_b32 (distinct values only)
__device__ __forceinline__ void pls(unsigned &a, unsigned &b) {
    asm("v_permlane32_swap_b32 %0, %1" : "+v"(a), "+v"(b));
}

// ---- Kernel 0: W -> Wp, fragment-packed bf16 B-frags [nt 12][ks 16][lane 64]x8
__global__ __launch_bounds__(256) void prep_w(
    const float* __restrict__ Wq, const float* __restrict__ Wk,
    const float* __restrict__ Wv, unsigned short* __restrict__ Wp)
{
    const int e = blockIdx.x * 256 + threadIdx.x;   // 48*256 = 12288 entries
    const int nt = e >> 10;
    const int ks = (e >> 6) & 15;
    const int l  = e & 63;
    const int col = nt * 16 + (l & 15);
    const int kb  = ks * 32 + (l >> 4) * 8;
    const float* W = (col < 64) ? Wq : ((col < 128) ? Wk : Wv);
    const int cc = col & 63;
    const float sc = (col < 64) ? SQSCALE : 1.f;
    union { unsigned short s[8]; ushort8 v; } u;
    #pragma unroll
    for (int j = 0; j < 8; ++j) u.s[j] = f2bf(W[(kb + j) * 64 + cc] * sc);
    *(ushort8*)&Wp[(size_t)e * 8] = u.v;
}

// ---- Kernel 1: QKV projection via bf16 MFMA; outputs ALL fragment-packed ---
__global__ __launch_bounds__(512, 4) void qkv_proj_kernel(
    const float* __restrict__ emb, const unsigned short* __restrict__ Wp,
    unsigned short* __restrict__ Qp, unsigned short* __restrict__ Kp,
    unsigned short* __restrict__ Vp)
{
    __shared__ unsigned short at[32][536];   // 33.5 KB
    __shared__ unsigned short qt[32][72];    // 4.6 KB  [q][dim]
    __shared__ unsigned short kt[32][72];    // 4.6 KB  [key][dim]
    __shared__ unsigned short vt[64][40];    // 5.1 KB  [dim][key]
    const int tid = threadIdx.x;
    const long row0 = (long)blockIdx.x * 32;

    // stage 32x512 emb rows as bf16 (coalesced float4 reads)
    {
        const int r = tid >> 4, c16 = tid & 15;
        const float* __restrict__ src = emb + (row0 + r) * 512;
        #pragma unroll
        for (int j = 0; j < 4; ++j) {
            const int col = j * 128 + c16 * 8;
            const float4 x0 = *(const float4*)(src + col);
            const float4 x1 = *(const float4*)(src + col + 4);
            u32x4 p;
            p[0] = cvtpk(x0.x, x0.y); p[1] = cvtpk(x0.z, x0.w);
            p[2] = cvtpk(x1.x, x1.y); p[3] = cvtpk(x1.z, x1.w);
            *(u32x4*)&at[r][col] = p;
        }
    }
    __syncthreads();

    const int w = tid >> 6, lane = tid & 63;
    const int c = lane & 15, hi = lane >> 4;
    const int rg = w & 1, ng = w >> 1;

    f32x4 acc[3];
    #pragma unroll
    for (int j = 0; j < 3; ++j) acc[j] = (f32x4){0.f, 0.f, 0.f, 0.f};

    #pragma unroll
    for (int ks = 0; ks < 16; ++ks) {
        const bf16x8 af = *(const bf16x8*)&at[rg * 16 + c][ks * 32 + hi * 8];
        #pragma unroll
        for (int j = 0; j < 3; ++j) {
            const int nt = ng * 3 + j;
            const bf16x8 bf_ = *(const bf16x8*)&Wp[((size_t)(nt * 16 + ks) * 64 + lane) * 8];
            acc[j] = __builtin_amdgcn_mfma_f32_16x16x32_bf16(af, bf_, acc[j], 0, 0, 0);
        }
    }

    // D-frag: row = hi*4+r4, col = c  -> all three into LDS transpose buffers
    #pragma unroll
    for (int j = 0; j < 3; ++j) {
        const int nt = ng * 3 + j;
        #pragma unroll
        for (int r4 = 0; r4 < 4; ++r4) {
            const int rloc = rg * 16 + hi * 4 + r4;
            const unsigned short v = f2bf(acc[j][r4]);
            if (nt < 4)       qt[rloc][nt * 16 + c] = v;
            else if (nt < 8)  kt[rloc][(nt - 4) * 16 + c] = v;
            else              vt[(nt - 8) * 16 + c][rloc] = v;
        }
    }
    __syncthreads();

    // fragment-pack Q, K, V (16B per thread per pass, coalesced stores)
    const int tloc = (int)(row0 & 4095);
    const long bb = row0 >> 12;
    const int ci  = tloc >> 6;
    const int f_  = (tloc >> 5) & 1;
    const int ks0 = (tloc >> 4) & 3;      // 0 or 2
    const int tt  = tloc >> 5;            // 32-q tile index 0..127
    if (tid < 256) {
        const int kk = tid >> 6, l = tid & 63;
        const ushort8 kval = *(const ushort8*)&kt[l & 31][kk * 16 + (l >> 5) * 8];
        *(ushort8*)&Kp[((((bb * 64 + ci) * 2 + f_) * 4 + kk) * 64 + l) * 8] = kval;
        const ushort8 qval = *(const ushort8*)&qt[l & 31][kk * 16 + (l >> 5) * 8];
        *(ushort8*)&Qp[(((bb * 128 + tt) * 4 + kk) * 64 + l) * 8] = qval;
    } else {
        const int e = tid - 256;
        const int ksl = e >> 7, ct = (e >> 6) & 1, l = e & 63;
        const ushort8 val = *(const ushort8*)&vt[ct * 32 + (l & 31)][ksl * 16 + (l >> 5) * 8];
        *(ushort8*)&Vp[((((bb * 64 + ci) * 4 + ks0 + ksl) * 2 + ct) * 64 + l) * 8] = val;
    }
}

// ---- Kernel 2: causal flash attention, persistent paired tiles -------------
// 256 blocks (1/CU) x 16 waves (4 waves/SIMD). Block (b, pp) processes tiles
// {127-pp, pp} sequentially; nc(t)+nc(127-t) == 65 exactly -> zero tail.
// 16-way in-block split-K per tile, 140 KB LDS merge -> out.
__global__ __launch_bounds__(1024, 4) void attn_kernel(
    const unsigned short* __restrict__ Qp, const unsigned short* __restrict__ Kp,
    const unsigned short* __restrict__ Vp, float* __restrict__ out)
{
    __shared__ float accbuf[16][32][68];   // 139.3 KB, [q][d] pad 68
    __shared__ float mbuf[16][32], lbuf[16][32];

    const int tid = threadIdx.x, w = tid >> 6, lane = tid & 63;
    const int c = lane & 31, h = lane >> 5;
    const int b = blockIdx.x & 3;
    const int pp = blockIdx.x >> 2;       // 0..63

    const unsigned short* __restrict__ Qpb = Qp + (size_t)b * 128 * 4 * 512;
    const unsigned short* __restrict__ Kpb = Kp + (size_t)b * 64 * 8 * 512;
    const unsigned short* __restrict__ Vpb = Vp + (size_t)b * 64 * 8 * 512;

    for (int ti = 0; ti < 2; ++ti) {
        const int t = ti ? pp : (127 - pp);
        const int qb = t << 5;
        const int nc = ((qb + 31) >> 6) + 1;

        // Q^T B-frags, lane-linear packed
        bf16x8 qf[4];
        #pragma unroll
        for (int kk = 0; kk < 4; ++kk)
            qf[kk] = *(const bf16x8*)&Qpb[(((size_t)t * 4 + kk) * 64 + lane) * 8];

        f32x16 acc[2];
        #pragma unroll
        for (int ct = 0; ct < 2; ++ct)
            #pragma unroll
            for (int j = 0; j < 16; ++j) acc[ct][j] = 0.f;
        float m = -1e30f, l = 0.f;

        // strength-reduced chunk pointers (chunk = 4096 ushorts; iter = 16 chunks)
        const unsigned short* kptr = Kpb + (size_t)w * 4096 + lane * 8;
        const unsigned short* vptr = Vpb + (size_t)w * 4096 + lane * 8;

        bf16x8 kf[2][4];
        {
            const unsigned short* kp0 = (w < nc) ? kptr : (kptr - (size_t)(w - nc + 1) * 4096);
            #pragma unroll
            for (int f = 0; f < 2; ++f)
                #pragma unroll
                for (int kk = 0; kk < 4; ++kk)
                    kf[f][kk] = *(const bf16x8*)&kp0[f * 2048 + kk * 512];
        }

        for (int ci = w; ci < nc; ci += 16) {
            const int s0 = ci << 6;

            bf16x8 vf[4][2];
            #pragma unroll
            for (int ks = 0; ks < 4; ++ks)
                #pragma unroll
                for (int ct = 0; ct < 2; ++ct)
                    vf[ks][ct] = *(const bf16x8*)&vptr[ks * 1024 + ct * 512];

            // S^T = K Q^T : D[row=key][col=q]
            f32x16 sf[2];
            #pragma unroll
            for (int f = 0; f < 2; ++f)
                #pragma unroll
                for (int j = 0; j < 16; ++j) sf[f][j] = 0.f;
            __builtin_amdgcn_s_setprio(1);
            #pragma unroll
            for (int f = 0; f < 2; ++f)
                #pragma unroll
                for (int kk = 0; kk < 4; ++kk)
                    sf[f] = __builtin_amdgcn_mfma_f32_32x32x16_bf16(kf[f][kk], qf[kk], sf[f], 0, 0, 0);
            __builtin_amdgcn_s_setprio(0);

            // prefetch next chunk's K (clamped; values unused past end)
            const unsigned short* knp = (ci + 16 < nc) ? (kptr + 65536) : kptr;
            bf16x8 kn[2][4];
            #pragma unroll
            for (int f = 0; f < 2; ++f)
                #pragma unroll
                for (int kk = 0; kk < 4; ++kk)
                    kn[f][kk] = *(const bf16x8*)&knp[f * 2048 + kk * 512];

            // causal mask: key = s0 + 32f + (r&3) + 8*(r>>2) + 4h ; q = qb + c
            if (s0 + 63 > qb) {
                #pragma unroll
                for (int f = 0; f < 2; ++f)
                    #pragma unroll
                    for (int r = 0; r < 16; ++r) {
                        const int key = s0 + f * 32 + ((r & 3) + 8 * (r >> 2)) + 4 * h;
                        if (key > qb + c) sf[f][r] = -1e30f;
                    }
            }

            // ---- online softmax (exp2 domain); 4-partial tree reductions ----
            float t0 = fmaxf(sf[0][0], sf[1][0]);
            float t1 = fmaxf(sf[0][1], sf[1][1]);
            float t2 = fmaxf(sf[0][2], sf[1][2]);
            float t3 = fmaxf(sf[0][3], sf[1][3]);
            #pragma unroll
            for (int r = 4; r < 16; r += 4) {
                t0 = fmaxf(t0, fmaxf(sf[0][r],     sf[1][r]));
                t1 = fmaxf(t1, fmaxf(sf[0][r + 1], sf[1][r + 1]));
                t2 = fmaxf(t2, fmaxf(sf[0][r + 2], sf[1][r + 2]));
                t3 = fmaxf(t3, fmaxf(sf[0][r + 3], sf[1][r + 3]));
            }
            float pm = fmaxf(fmaxf(t0, t1), fmaxf(t2, t3));
            pm = fmaxf(pm, __shfl_xor(pm, 32));

            float mn = m;
            if (__any(pm > m)) {           // exact skip: if no column grew, sc == 1
                mn = fmaxf(m, pm);
                const float sc = exp2f(m - mn);   // per-lane scalar (q = c)
                m = mn;
                l *= sc;
                #pragma unroll
                for (int ct = 0; ct < 2; ++ct)
                    #pragma unroll
                    for (int r = 0; r < 16; ++r) acc[ct][r] *= sc;
            }

            float s0a = 0.f, s1a = 0.f, s2a = 0.f, s3a = 0.f;
            #pragma unroll
            for (int f = 0; f < 2; ++f)
                #pragma unroll
                for (int r = 0; r < 16; r += 4) {
                    float p0 = exp2f(sf[f][r] - mn);
                    float p1 = exp2f(sf[f][r + 1] - mn);
                    float p2 = exp2f(sf[f][r + 2] - mn);
                    float p3 = exp2f(sf[f][r + 3] - mn);
                    sf[f][r] = p0; sf[f][r + 1] = p1; sf[f][r + 2] = p2; sf[f][r + 3] = p3;
                    s0a += p0; s1a += p1; s2a += p2; s3a += p3;
                }
            float rs = (s0a + s1a) + (s2a + s3a);
            rs += __shfl_xor(rs, 32);
            l += rs;

            // ---- P -> bf16 frags via cvt_pk + permlane32_swap; O^T += V^T P --
            #pragma unroll
            for (int f = 0; f < 2; ++f) {
                unsigned w01 = cvtpk(sf[f][0], sf[f][1]);
                unsigned w23 = cvtpk(sf[f][2], sf[f][3]);
                unsigned w45 = cvtpk(sf[f][4], sf[f][5]);
                unsigned w67 = cvtpk(sf[f][6], sf[f][7]);
                pls(w01, w45); pls(w23, w67);
                union { unsigned uu[4]; bf16x8 v; } pa0, pa1;
                pa0.uu[0] = w01; pa0.uu[1] = w23; pa0.uu[2] = w45; pa0.uu[3] = w67;
                unsigned x01 = cvtpk(sf[f][8],  sf[f][9]);
                unsigned x23 = cvtpk(sf[f][10], sf[f][11]);
                unsigned x45 = cvtpk(sf[f][12], sf[f][13]);
                unsigned x67 = cvtpk(sf[f][14], sf[f][15]);
                pls(x01, x45); pls(x23, x67);
                pa1.uu[0] = x01; pa1.uu[1] = x23; pa1.uu[2] = x45; pa1.uu[3] = x67;
                __builtin_amdgcn_s_setprio(1);
                #pragma unroll
                for (int ct = 0; ct < 2; ++ct) {
                    acc[ct] = __builtin_amdgcn_mfma_f32_32x32x16_bf16(vf[2 * f][ct],     pa0.v, acc[ct], 0, 0, 0);
                    acc[ct] = __builtin_amdgcn_mfma_f32_32x32x16_bf16(vf[2 * f + 1][ct], pa1.v, acc[ct], 0, 0, 0);
                }
                __builtin_amdgcn_s_setprio(0);
            }

            #pragma unroll
            for (int f = 0; f < 2; ++f)
                #pragma unroll
                for (int kk = 0; kk < 4; ++kk) kf[f][kk] = kn[f][kk];
            kptr += 65536;
            vptr += 65536;
        }

        // ---- split-K merge: D col = q = c, row = d = ct*32 + 8g + 4h + 0..3 --
        if (h == 0) { mbuf[w][c] = m; lbuf[w][c] = l; }
        #pragma unroll
        for (int ct = 0; ct < 2; ++ct)
            #pragma unroll
            for (int g = 0; g < 4; ++g)
                *(float4*)&accbuf[w][c][ct * 32 + g * 8 + 4 * h] =
                    make_float4(acc[ct][4 * g], acc[ct][4 * g + 1],
                                acc[ct][4 * g + 2], acc[ct][4 * g + 3]);
        __syncthreads();
        #pragma unroll
        for (int i = 0; i < 2; ++i) {
            const int e = tid + i * 1024;
            const int q = e >> 6, d = e & 63;
            float ms = mbuf[0][q];
            #pragma unroll
            for (int wv = 1; wv < 16; ++wv) ms = fmaxf(ms, mbuf[wv][q]);
            float ls = 0.f, os = 0.f;
            #pragma unroll
            for (int wv = 0; wv < 16; ++wv) {
                const float e_ = exp2f(mbuf[wv][q] - ms);
                ls += lbuf[wv][q] * e_;
                os += accbuf[wv][q][d] * e_;
            }
            out[((long)b * T_ + qb + q) * 64 + d] = os / ls;
        }
        __syncthreads();   // protect accbuf/mbuf/lbuf reuse by next tile
    }
}

extern "C" void kernel_launch(void* const* d_in, const int* in_sizes, int n_in,
                              void* d_out, int out_size, void* d_ws, size_t ws_size,
                              hipStream_t stream)
{
    const float* emb = (const float*)d_in[0];
    const float* Wq  = (const float*)d_in[1];
    const float* Wk  = (const float*)d_in[2];
    const float* Wv  = (const float*)d_in[3];
    float* out = (float*)d_out;

    unsigned short* Qp = (unsigned short*)d_ws;         // 2 MB packed Q frags
    unsigned short* Kp = Qp + (size_t)B_ * T_ * A_;     // 2 MB packed K frags
    unsigned short* Vp = Kp + (size_t)B_ * T_ * A_;     // 2 MB packed V frags
    unsigned short* Wp = Vp + (size_t)B_ * T_ * A_;     // 192 KB packed W frags

    prep_w<<<dim3(48), dim3(256), 0, stream>>>(Wq, Wk, Wv, Wp);
    qkv_proj_kernel<<<dim3(512), dim3(512), 0, stream>>>(emb, Wp, Qp, Kp, Vp);
    attn_kernel<<<dim3(256), dim3(1024), 0, stream>>>(Qp, Kp, Vp, out);
}

// Round 16
// 47.635 us; speedup vs baseline: 2.0347x; 2.0347x over previous
//
#include <hip/hip_runtime.h>

#define B_ 4
#define T_ 4096
#define E_ 512
#define A_ 64
#define SQSCALE 0.1803368801111204f   // log2(e)/8 : folds softmax scale + exp->exp2

typedef __attribute__((ext_vector_type(8)))  short bf16x8;
typedef __attribute__((ext_vector_type(8)))  unsigned short ushort8;
typedef __attribute__((ext_vector_type(4)))  unsigned int   u32x4;
typedef __attribute__((ext_vector_type(4)))  float f32x4;
typedef __attribute__((ext_vector_type(16))) float f32x16;

__device__ __forceinline__ unsigned short f2bf(float x) {
    union { float f; unsigned int u; } v; v.f = x;
    unsigned int r = v.u + 0x7fffu + ((v.u >> 16) & 1u);
    return (unsigned short)(r >> 16);
}
__device__ __forceinline__ unsigned cvtpk(float a, float b) {
    unsigned r;
    asm("v_cvt_pk_bf16_f32 %0, %1, %2" : "=v"(r) : "v"(a), "v"(b));
    return r;
}
// v_permlane32_swap_b32 (distinct values only)
__device__ __forceinline__ void pls(unsigned &a, unsigned &b) {
    asm("v_permlane32_swap_b32 %0, %1" : "+v"(a), "+v"(b));
}

// ---- Kernel 0: W -> Wp, fragment-packed bf16 B-frags [nt 12][ks 16][lane 64]x8
__global__ __launch_bounds__(256) void prep_w(
    const float* __restrict__ Wq, const float* __restrict__ Wk,
    const float* __restrict__ Wv, unsigned short* __restrict__ Wp)
{
    const int e = blockIdx.x * 256 + threadIdx.x;   // 48*256 = 12288 entries
    const int nt = e >> 10;
    const int ks = (e >> 6) & 15;
    const int l  = e & 63;
    const int col = nt * 16 + (l & 15);
    const int kb  = ks * 32 + (l >> 4) * 8;
    const float* W = (col < 64) ? Wq : ((col < 128) ? Wk : Wv);
    const int cc = col & 63;
    const float sc = (col < 64) ? SQSCALE : 1.f;
    union { unsigned short s[8]; ushort8 v; } u;
    #pragma unroll
    for (int j = 0; j < 8; ++j) u.s[j] = f2bf(W[(kb + j) * 64 + cc] * sc);
    *(ushort8*)&Wp[(size_t)e * 8] = u.v;
}

// ---- Kernel 1: QKV projection via bf16 MFMA, 64-row blocks -----------------
// 256 blocks x 512 threads. Wave (rg2 = w>>2, ng = w&3): 2 A-frags (16 rows
// each) x 3 nt-tiles per B-frag load -> halves Wp L2 traffic (196->98 MB).
// qt/kt/vt alias the dead `at` buffer after the MFMA loop (68.6 KB LDS).
// Block = exactly one K-chunk + one V-chunk + two Q-tiles, packed coalesced.
__global__ __launch_bounds__(512, 1) void qkv_proj_kernel(
    const float* __restrict__ emb, const unsigned short* __restrict__ Wp,
    unsigned short* __restrict__ Qp, unsigned short* __restrict__ Kp,
    unsigned short* __restrict__ Vp)
{
    __shared__ unsigned short lds[64 * 536];   // 68.6 KB
    unsigned short (*at)[536] = (unsigned short (*)[536])lds;
    unsigned short (*qt)[72]  = (unsigned short (*)[72])lds;           // [q 64][dim]
    unsigned short (*kt)[72]  = (unsigned short (*)[72])(lds + 4608);  // [key 64][dim]
    unsigned short (*vt)[72]  = (unsigned short (*)[72])(lds + 9216);  // [dim 64][key]
    const int tid = threadIdx.x;
    const long row0 = (long)blockIdx.x * 64;

    // ---- stage 64x512 emb rows as bf16 (coalesced float4 reads) ----
    {
        const int r = tid >> 3, c8 = tid & 7;
        const float* __restrict__ src = emb + (row0 + r) * 512;
        #pragma unroll
        for (int j = 0; j < 8; ++j) {
            const int col = j * 64 + c8 * 8;
            const float4 x0 = *(const float4*)(src + col);
            const float4 x1 = *(const float4*)(src + col + 4);
            u32x4 p;
            p[0] = cvtpk(x0.x, x0.y); p[1] = cvtpk(x0.z, x0.w);
            p[2] = cvtpk(x1.x, x1.y); p[3] = cvtpk(x1.z, x1.w);
            *(u32x4*)&at[r][col] = p;
        }
    }
    __syncthreads();

    const int w = tid >> 6, lane = tid & 63;
    const int c = lane & 15, hi = lane >> 4;
    const int rg2 = w >> 2, ng = w & 3;     // rg2: rows rg2*32..+31; ng: 3 nt tiles

    f32x4 acc[2][3];
    #pragma unroll
    for (int rr = 0; rr < 2; ++rr)
        #pragma unroll
        for (int j = 0; j < 3; ++j) acc[rr][j] = (f32x4){0.f, 0.f, 0.f, 0.f};

    #pragma unroll
    for (int ks = 0; ks < 16; ++ks) {
        const bf16x8 a0 = *(const bf16x8*)&at[rg2 * 32 + c][ks * 32 + hi * 8];
        const bf16x8 a1 = *(const bf16x8*)&at[rg2 * 32 + 16 + c][ks * 32 + hi * 8];
        #pragma unroll
        for (int j = 0; j < 3; ++j) {
            const int nt = ng * 3 + j;
            const bf16x8 bf_ = *(const bf16x8*)&Wp[((size_t)(nt * 16 + ks) * 64 + lane) * 8];
            acc[0][j] = __builtin_amdgcn_mfma_f32_16x16x32_bf16(a0, bf_, acc[0][j], 0, 0, 0);
            acc[1][j] = __builtin_amdgcn_mfma_f32_16x16x32_bf16(a1, bf_, acc[1][j], 0, 0, 0);
        }
    }
    __syncthreads();   // all `at` reads complete before aliased qt/kt/vt writes

    // D-frag: row = rg2*32 + rr*16 + hi*4 + r4, col = c
    #pragma unroll
    for (int j = 0; j < 3; ++j) {
        const int nt = ng * 3 + j;
        #pragma unroll
        for (int rr = 0; rr < 2; ++rr)
            #pragma unroll
            for (int r4 = 0; r4 < 4; ++r4) {
                const int rloc = rg2 * 32 + rr * 16 + hi * 4 + r4;
                const unsigned short v = f2bf(acc[rr][j][r4]);
                if (nt < 4)       qt[rloc][nt * 16 + c] = v;
                else if (nt < 8)  kt[rloc][(nt - 4) * 16 + c] = v;
                else              vt[(nt - 8) * 16 + c][rloc] = v;
            }
    }
    __syncthreads();

    // ---- fragment-pack: block = 1 chunk (K, V) + 2 tiles (Q), 3x16B/thread --
    const long bb = row0 >> 12;
    const int ci  = (int)(row0 & 4095) >> 6;
    const int tt0 = (int)(row0 & 4095) >> 5;
    const int l = tid & 63;
    {
        const int f = tid >> 8, kk = (tid >> 6) & 3;
        const ushort8 kval = *(const ushort8*)&kt[f * 32 + (l & 31)][kk * 16 + (l >> 5) * 8];
        *(ushort8*)&Kp[((((bb * 64 + ci) * 2 + f) * 4 + kk) * 64 + l) * 8] = kval;
        const ushort8 qval = *(const ushort8*)&qt[f * 32 + (l & 31)][kk * 16 + (l >> 5) * 8];
        *(ushort8*)&Qp[(((bb * 128 + tt0 + f) * 4 + kk) * 64 + l) * 8] = qval;
    }
    {
        const int ks_ = tid >> 7, ct = (tid >> 6) & 1;
        const ushort8 vval = *(const ushort8*)&vt[ct * 32 + (l & 31)][ks_ * 16 + (l >> 5) * 8];
        *(ushort8*)&Vp[((((bb * 64 + ci) * 4 + ks_) * 2 + ct) * 64 + l) * 8] = vval;
    }
}

// ---- Kernel 2: causal flash attention, persistent paired tiles (R14) -------
// 256 blocks (1/CU), 8 waves. Block (b, pp) processes tiles {127-pp, pp}
// sequentially; nc(t)+nc(127-t) == 66 exactly -> zero tail. 8-way in-block
// split-K per tile, LDS merge -> out.
__global__ __launch_bounds__(512, 1) void attn_kernel(
    const unsigned short* __restrict__ Qp, const unsigned short* __restrict__ Kp,
    const unsigned short* __restrict__ Vp, float* __restrict__ out)
{
    __shared__ float accbuf[8][32][68];   // 69.6 KB, [q][d] pad 68
    __shared__ float mbuf[8][32], lbuf[8][32];

    const int tid = threadIdx.x, w = tid >> 6, lane = tid & 63;
    const int c = lane & 31, h = lane >> 5;
    const int b = blockIdx.x & 3;
    const int pp = blockIdx.x >> 2;       // 0..63

    const unsigned short* __restrict__ Qpb = Qp + (size_t)b * 128 * 4 * 512;
    const unsigned short* __restrict__ Kpb = Kp + (size_t)b * 64 * 8 * 512;
    const unsigned short* __restrict__ Vpb = Vp + (size_t)b * 64 * 8 * 512;

    for (int ti = 0; ti < 2; ++ti) {
        const int t = ti ? pp : (127 - pp);
        const int qb = t << 5;
        const int nc = ((qb + 31) >> 6) + 1;

        // Q^T B-frags, lane-linear packed
        bf16x8 qf[4];
        #pragma unroll
        for (int kk = 0; kk < 4; ++kk)
            qf[kk] = *(const bf16x8*)&Qpb[(((size_t)t * 4 + kk) * 64 + lane) * 8];

        f32x16 acc[2];
        #pragma unroll
        for (int ct = 0; ct < 2; ++ct)
            #pragma unroll
            for (int j = 0; j < 16; ++j) acc[ct][j] = 0.f;
        float m = -1e30f, l = 0.f;

        // strength-reduced chunk pointers (chunk = 4096 ushorts; iter = 8 chunks)
        const unsigned short* kptr = Kpb + (size_t)w * 4096 + lane * 8;
        const unsigned short* vptr = Vpb + (size_t)w * 4096 + lane * 8;

        bf16x8 kf[2][4];
        {
            const unsigned short* kp0 = (w < nc) ? kptr : (kptr - (size_t)(w - nc + 1) * 4096);
            #pragma unroll
            for (int f = 0; f < 2; ++f)
                #pragma unroll
                for (int kk = 0; kk < 4; ++kk)
                    kf[f][kk] = *(const bf16x8*)&kp0[f * 2048 + kk * 512];
        }

        for (int ci = w; ci < nc; ci += 8) {
            const int s0 = ci << 6;

            bf16x8 vf[4][2];
            #pragma unroll
            for (int ks = 0; ks < 4; ++ks)
                #pragma unroll
                for (int ct = 0; ct < 2; ++ct)
                    vf[ks][ct] = *(const bf16x8*)&vptr[ks * 1024 + ct * 512];

            // S^T = K Q^T : D[row=key][col=q]
            f32x16 sf[2];
            #pragma unroll
            for (int f = 0; f < 2; ++f)
                #pragma unroll
                for (int j = 0; j < 16; ++j) sf[f][j] = 0.f;
            __builtin_amdgcn_s_setprio(1);
            #pragma unroll
            for (int f = 0; f < 2; ++f)
                #pragma unroll
                for (int kk = 0; kk < 4; ++kk)
                    sf[f] = __builtin_amdgcn_mfma_f32_32x32x16_bf16(kf[f][kk], qf[kk], sf[f], 0, 0, 0);
            __builtin_amdgcn_s_setprio(0);

            // prefetch next chunk's K (clamped; values unused past end)
            const unsigned short* knp = (ci + 8 < nc) ? (kptr + 32768) : kptr;
            bf16x8 kn[2][4];
            #pragma unroll
            for (int f = 0; f < 2; ++f)
                #pragma unroll
                for (int kk = 0; kk < 4; ++kk)
                    kn[f][kk] = *(const bf16x8*)&knp[f * 2048 + kk * 512];

            // causal mask: key = s0 + 32f + (r&3) + 8*(r>>2) + 4h ; q = qb + c
            if (s0 + 63 > qb) {
                #pragma unroll
                for (int f = 0; f < 2; ++f)
                    #pragma unroll
                    for (int r = 0; r < 16; ++r) {
                        const int key = s0 + f * 32 + ((r & 3) + 8 * (r >> 2)) + 4 * h;
                        if (key > qb + c) sf[f][r] = -1e30f;
                    }
            }

            // ---- online softmax (exp2 domain); 4-partial tree reductions ----
            float t0 = fmaxf(sf[0][0], sf[1][0]);
            float t1 = fmaxf(sf[0][1], sf[1][1]);
            float t2 = fmaxf(sf[0][2], sf[1][2]);
            float t3 = fmaxf(sf[0][3], sf[1][3]);
            #pragma unroll
            for (int r = 4; r < 16; r += 4) {
                t0 = fmaxf(t0, fmaxf(sf[0][r],     sf[1][r]));
                t1 = fmaxf(t1, fmaxf(sf[0][r + 1], sf[1][r + 1]));
                t2 = fmaxf(t2, fmaxf(sf[0][r + 2], sf[1][r + 2]));
                t3 = fmaxf(t3, fmaxf(sf[0][r + 3], sf[1][r + 3]));
            }
            float pm = fmaxf(fmaxf(t0, t1), fmaxf(t2, t3));
            pm = fmaxf(pm, __shfl_xor(pm, 32));

            float mn = m;
            if (__any(pm > m)) {           // exact skip: if no column grew, sc == 1
                mn = fmaxf(m, pm);
                const float sc = exp2f(m - mn);   // per-lane scalar (q = c)
                m = mn;
                l *= sc;
                #pragma unroll
                for (int ct = 0; ct < 2; ++ct)
                    #pragma unroll
                    for (int r = 0; r < 16; ++r) acc[ct][r] *= sc;
            }

            float s0a = 0.f, s1a = 0.f, s2a = 0.f, s3a = 0.f;
            #pragma unroll
            for (int f = 0; f < 2; ++f)
                #pragma unroll
                for (int r = 0; r < 16; r += 4) {
                    float p0 = exp2f(sf[f][r] - mn);
                    float p1 = exp2f(sf[f][r + 1] - mn);
                    float p2 = exp2f(sf[f][r + 2] - mn);
                    float p3 = exp2f(sf[f][r + 3] - mn);
                    sf[f][r] = p0; sf[f][r + 1] = p1; sf[f][r + 2] = p2; sf[f][r + 3] = p3;
                    s0a += p0; s1a += p1; s2a += p2; s3a += p3;
                }
            float rs = (s0a + s1a) + (s2a + s3a);
            rs += __shfl_xor(rs, 32);
            l += rs;

            // ---- P -> bf16 frags via cvt_pk + permlane32_swap; O^T += V^T P --
            #pragma unroll
            for (int f = 0; f < 2; ++f) {
                unsigned w01 = cvtpk(sf[f][0], sf[f][1]);
                unsigned w23 = cvtpk(sf[f][2], sf[f][3]);
                unsigned w45 = cvtpk(sf[f][4], sf[f][5]);
                unsigned w67 = cvtpk(sf[f][6], sf[f][7]);
                pls(w01, w45); pls(w23, w67);
                union { unsigned uu[4]; bf16x8 v; } pa0, pa1;
                pa0.uu[0] = w01; pa0.uu[1] = w23; pa0.uu[2] = w45; pa0.uu[3] = w67;
                unsigned x01 = cvtpk(sf[f][8],  sf[f][9]);
                unsigned x23 = cvtpk(sf[f][10], sf[f][11]);
                unsigned x45 = cvtpk(sf[f][12], sf[f][13]);
                unsigned x67 = cvtpk(sf[f][14], sf[f][15]);
                pls(x01, x45); pls(x23, x67);
                pa1.uu[0] = x01; pa1.uu[1] = x23; pa1.uu[2] = x45; pa1.uu[3] = x67;
                __builtin_amdgcn_s_setprio(1);
                #pragma unroll
                for (int ct = 0; ct < 2; ++ct) {
                    acc[ct] = __builtin_amdgcn_mfma_f32_32x32x16_bf16(vf[2 * f][ct],     pa0.v, acc[ct], 0, 0, 0);
                    acc[ct] = __builtin_amdgcn_mfma_f32_32x32x16_bf16(vf[2 * f + 1][ct], pa1.v, acc[ct], 0, 0, 0);
                }
                __builtin_amdgcn_s_setprio(0);
            }

            #pragma unroll
            for (int f = 0; f < 2; ++f)
                #pragma unroll
                for (int kk = 0; kk < 4; ++kk) kf[f][kk] = kn[f][kk];
            kptr += 32768;
            vptr += 32768;
        }

        // ---- split-K merge: D col = q = c, row = d = ct*32 + 8g + 4h + 0..3 --
        if (h == 0) { mbuf[w][c] = m; lbuf[w][c] = l; }
        #pragma unroll
        for (int ct = 0; ct < 2; ++ct)
            #pragma unroll
            for (int g = 0; g < 4; ++g)
                *(float4*)&accbuf[w][c][ct * 32 + g * 8 + 4 * h] =
                    make_float4(acc[ct][4 * g], acc[ct][4 * g + 1],
                                acc[ct][4 * g + 2], acc[ct][4 * g + 3]);
        __syncthreads();
        #pragma unroll
        for (int i = 0; i < 4; ++i) {
            const int e = tid + i * 512;
            const int q = e >> 6, d = e & 63;
            float ms = mbuf[0][q];
            #pragma unroll
            for (int wv = 1; wv < 8; ++wv) ms = fmaxf(ms, mbuf[wv][q]);
            float ls = 0.f, os = 0.f;
            #pragma unroll
            for (int wv = 0; wv < 8; ++wv) {
                const float e_ = exp2f(mbuf[wv][q] - ms);
                ls += lbuf[wv][q] * e_;
                os += accbuf[wv][q][d] * e_;
            }
            out[((long)b * T_ + qb + q) * 64 + d] = os / ls;
        }
        __syncthreads();   // protect accbuf/mbuf/lbuf reuse by next tile
    }
}

extern "C" void kernel_launch(void* const* d_in, const int* in_sizes, int n_in,
                              void* d_out, int out_size, void* d_ws, size_t ws_size,
                              hipStream_t stream)
{
    const float* emb = (const float*)d_in[0];
    const float* Wq  = (const float*)d_in[1];
    const float* Wk  = (const float*)d_in[2];
    const float* Wv  = (const float*)d_in[3];
    float* out = (float*)d_out;

    unsigned short* Qp = (unsigned short*)d_ws;         // 2 MB packed Q frags
    unsigned short* Kp = Qp + (size_t)B_ * T_ * A_;     // 2 MB packed K frags
    unsigned short* Vp = Kp + (size_t)B_ * T_ * A_;     // 2 MB packed V frags
    unsigned short* Wp = Vp + (size_t)B_ * T_ * A_;     // 192 KB packed W frags

    prep_w<<<dim3(48), dim3(256), 0, stream>>>(Wq, Wk, Wv, Wp);
    qkv_proj_kernel<<<dim3(256), dim3(512), 0, stream>>>(emb, Wp, Qp, Kp, Vp);
    attn_kernel<<<dim3(256), dim3(512), 0, stream>>>(Qp, Kp, Vp, out);
}

// Round 17
// 44.729 us; speedup vs baseline: 2.1668x; 1.0650x over previous
//
#include <hip/hip_runtime.h>

#define B_ 4
#define T_ 4096
#define E_ 512
#define A_ 64
#define SQSCALE 0.1803368801111204f   // log2(e)/8 : folds softmax scale + exp->exp2

typedef __attribute__((ext_vector_type(8)))  short bf16x8;
typedef __attribute__((ext_vector_type(8)))  unsigned short ushort8;
typedef __attribute__((ext_vector_type(4)))  unsigned int   u32x4;
typedef __attribute__((ext_vector_type(4)))  float f32x4;
typedef __attribute__((ext_vector_type(16))) float f32x16;

__device__ __forceinline__ unsigned short f2bf(float x) {
    union { float f; unsigned int u; } v; v.f = x;
    unsigned int r = v.u + 0x7fffu + ((v.u >> 16) & 1u);
    return (unsigned short)(r >> 16);
}
__device__ __forceinline__ unsigned cvtpk(float a, float b) {
    unsigned r;
    asm("v_cvt_pk_bf16_f32 %0, %1, %2" : "=v"(r) : "v"(a), "v"(b));
    return r;
}
// v_permlane32_swap_b32 (distinct values only)
__device__ __forceinline__ void pls(unsigned &a, unsigned &b) {
    asm("v_permlane32_swap_b32 %0, %1" : "+v"(a), "+v"(b));
}

// ---- Kernel 0: W -> Wp, fragment-packed bf16 B-frags [nt 12][ks 16][lane 64]x8
__global__ __launch_bounds__(256) void prep_w(
    const float* __restrict__ Wq, const float* __restrict__ Wk,
    const float* __restrict__ Wv, unsigned short* __restrict__ Wp)
{
    const int e = blockIdx.x * 256 + threadIdx.x;   // 48*256 = 12288 entries
    const int nt = e >> 10;
    const int ks = (e >> 6) & 15;
    const int l  = e & 63;
    const int col = nt * 16 + (l & 15);
    const int kb  = ks * 32 + (l >> 4) * 8;
    const float* W = (col < 64) ? Wq : ((col < 128) ? Wk : Wv);
    const int cc = col & 63;
    const float sc = (col < 64) ? SQSCALE : 1.f;
    union { unsigned short s[8]; ushort8 v; } u;
    #pragma unroll
    for (int j = 0; j < 8; ++j) u.s[j] = f2bf(W[(kb + j) * 64 + cc] * sc);
    *(ushort8*)&Wp[(size_t)e * 8] = u.v;
}

// ---- Kernel 1: QKV projection via bf16 MFMA ---------------------------------
// 512 blocks x 768 threads (12 waves), 32 rows/block, 47.8 KB LDS ->
// 2 blocks/CU = 24 waves/CU. Wave w owns nt-tile w and computes BOTH 16-row
// groups (2 MFMA per B-frag load) -> each B-frag read exactly once per block:
// Wp L2 traffic 384 KB -> 192 KB/block (98 MB total) at FULL occupancy
// (R8/R16 lesson: traffic cuts only pay if occupancy is preserved).
__global__ __launch_bounds__(768, 4) void qkv_proj_kernel(
    const float* __restrict__ emb, const unsigned short* __restrict__ Wp,
    unsigned short* __restrict__ Qp, unsigned short* __restrict__ Kp,
    unsigned short* __restrict__ Vp)
{
    __shared__ unsigned short at[32][536];   // 33.5 KB
    __shared__ unsigned short qt[32][72];    // 4.6 KB  [q][dim]
    __shared__ unsigned short kt[32][72];    // 4.6 KB  [key][dim]
    __shared__ unsigned short vt[64][40];    // 5.1 KB  [dim][key]
    const int tid = threadIdx.x;
    const long row0 = (long)blockIdx.x * 32;

    // stage 32x512 emb rows as bf16 (coalesced float4 reads; threads 0..511)
    if (tid < 512) {
        const int r = tid >> 4, c16 = tid & 15;
        const float* __restrict__ src = emb + (row0 + r) * 512;
        #pragma unroll
        for (int j = 0; j < 4; ++j) {
            const int col = j * 128 + c16 * 8;
            const float4 x0 = *(const float4*)(src + col);
            const float4 x1 = *(const float4*)(src + col + 4);
            u32x4 p;
            p[0] = cvtpk(x0.x, x0.y); p[1] = cvtpk(x0.z, x0.w);
            p[2] = cvtpk(x1.x, x1.y); p[3] = cvtpk(x1.z, x1.w);
            *(u32x4*)&at[r][col] = p;
        }
    }
    __syncthreads();

    const int w = tid >> 6, lane = tid & 63;   // w = nt tile index, 0..11
    const int c = lane & 15, hi = lane >> 4;

    f32x4 acc[2];
    acc[0] = (f32x4){0.f, 0.f, 0.f, 0.f};
    acc[1] = (f32x4){0.f, 0.f, 0.f, 0.f};

    #pragma unroll
    for (int ks = 0; ks < 16; ++ks) {
        const bf16x8 bf_ = *(const bf16x8*)&Wp[((size_t)(w * 16 + ks) * 64 + lane) * 8];
        const bf16x8 a0 = *(const bf16x8*)&at[c][ks * 32 + hi * 8];
        const bf16x8 a1 = *(const bf16x8*)&at[16 + c][ks * 32 + hi * 8];
        acc[0] = __builtin_amdgcn_mfma_f32_16x16x32_bf16(a0, bf_, acc[0], 0, 0, 0);
        acc[1] = __builtin_amdgcn_mfma_f32_16x16x32_bf16(a1, bf_, acc[1], 0, 0, 0);
    }

    // D-frag: row = rr*16 + hi*4 + r4, col = c ; nt = w
    #pragma unroll
    for (int rr = 0; rr < 2; ++rr)
        #pragma unroll
        for (int r4 = 0; r4 < 4; ++r4) {
            const int rloc = rr * 16 + hi * 4 + r4;
            const unsigned short v = f2bf(acc[rr][r4]);
            if (w < 4)       qt[rloc][w * 16 + c] = v;
            else if (w < 8)  kt[rloc][(w - 4) * 16 + c] = v;
            else             vt[(w - 8) * 16 + c][rloc] = v;
        }
    __syncthreads();

    // fragment-pack Q, K, V (one 16B entry per thread; threads 0..511)
    const int tloc = (int)(row0 & 4095);
    const long bb = row0 >> 12;
    const int ci  = tloc >> 6;
    const int f_  = (tloc >> 5) & 1;
    const int ks0 = (tloc >> 4) & 3;      // 0 or 2
    const int tt  = tloc >> 5;            // 32-q tile index 0..127
    if (tid < 256) {
        const int kk = tid >> 6, l = tid & 63;
        const ushort8 kval = *(const ushort8*)&kt[l & 31][kk * 16 + (l >> 5) * 8];
        *(ushort8*)&Kp[((((bb * 64 + ci) * 2 + f_) * 4 + kk) * 64 + l) * 8] = kval;
        const ushort8 qval = *(const ushort8*)&qt[l & 31][kk * 16 + (l >> 5) * 8];
        *(ushort8*)&Qp[(((bb * 128 + tt) * 4 + kk) * 64 + l) * 8] = qval;
    } else if (tid < 512) {
        const int e = tid - 256;
        const int ksl = e >> 7, ct = (e >> 6) & 1, l = e & 63;
        const ushort8 val = *(const ushort8*)&vt[ct * 32 + (l & 31)][ksl * 16 + (l >> 5) * 8];
        *(ushort8*)&Vp[((((bb * 64 + ci) * 4 + ks0 + ksl) * 2 + ct) * 64 + l) * 8] = val;
    }
}

// ---- Kernel 2: causal flash attention, persistent paired tiles (R14) -------
// 256 blocks (1/CU), 8 waves. Block (b, pp) processes tiles {127-pp, pp}
// sequentially; nc(t)+nc(127-t) == 66 exactly -> zero tail. 8-way in-block
// split-K per tile, LDS merge -> out.
__global__ __launch_bounds__(512, 1) void attn_kernel(
    const unsigned short* __restrict__ Qp, const unsigned short* __restrict__ Kp,
    const unsigned short* __restrict__ Vp, float* __restrict__ out)
{
    __shared__ float accbuf[8][32][68];   // 69.6 KB, [q][d] pad 68
    __shared__ float mbuf[8][32], lbuf[8][32];

    const int tid = threadIdx.x, w = tid >> 6, lane = tid & 63;
    const int c = lane & 31, h = lane >> 5;
    const int b = blockIdx.x & 3;
    const int pp = blockIdx.x >> 2;       // 0..63

    const unsigned short* __restrict__ Qpb = Qp + (size_t)b * 128 * 4 * 512;
    const unsigned short* __restrict__ Kpb = Kp + (size_t)b * 64 * 8 * 512;
    const unsigned short* __restrict__ Vpb = Vp + (size_t)b * 64 * 8 * 512;

    for (int ti = 0; ti < 2; ++ti) {
        const int t = ti ? pp : (127 - pp);
        const int qb = t << 5;
        const int nc = ((qb + 31) >> 6) + 1;

        // Q^T B-frags, lane-linear packed
        bf16x8 qf[4];
        #pragma unroll
        for (int kk = 0; kk < 4; ++kk)
            qf[kk] = *(const bf16x8*)&Qpb[(((size_t)t * 4 + kk) * 64 + lane) * 8];

        f32x16 acc[2];
        #pragma unroll
        for (int ct = 0; ct < 2; ++ct)
            #pragma unroll
            for (int j = 0; j < 16; ++j) acc[ct][j] = 0.f;
        float m = -1e30f, l = 0.f;

        // strength-reduced chunk pointers (chunk = 4096 ushorts; iter = 8 chunks)
        const unsigned short* kptr = Kpb + (size_t)w * 4096 + lane * 8;
        const unsigned short* vptr = Vpb + (size_t)w * 4096 + lane * 8;

        bf16x8 kf[2][4];
        {
            const unsigned short* kp0 = (w < nc) ? kptr : (kptr - (size_t)(w - nc + 1) * 4096);
            #pragma unroll
            for (int f = 0; f < 2; ++f)
                #pragma unroll
                for (int kk = 0; kk < 4; ++kk)
                    kf[f][kk] = *(const bf16x8*)&kp0[f * 2048 + kk * 512];
        }

        for (int ci = w; ci < nc; ci += 8) {
            const int s0 = ci << 6;

            bf16x8 vf[4][2];
            #pragma unroll
            for (int ks = 0; ks < 4; ++ks)
                #pragma unroll
                for (int ct = 0; ct < 2; ++ct)
                    vf[ks][ct] = *(const bf16x8*)&vptr[ks * 1024 + ct * 512];

            // S^T = K Q^T : D[row=key][col=q]
            f32x16 sf[2];
            #pragma unroll
            for (int f = 0; f < 2; ++f)
                #pragma unroll
                for (int j = 0; j < 16; ++j) sf[f][j] = 0.f;
            __builtin_amdgcn_s_setprio(1);
            #pragma unroll
            for (int f = 0; f < 2; ++f)
                #pragma unroll
                for (int kk = 0; kk < 4; ++kk)
                    sf[f] = __builtin_amdgcn_mfma_f32_32x32x16_bf16(kf[f][kk], qf[kk], sf[f], 0, 0, 0);
            __builtin_amdgcn_s_setprio(0);

            // prefetch next chunk's K (clamped; values unused past end)
            const unsigned short* knp = (ci + 8 < nc) ? (kptr + 32768) : kptr;
            bf16x8 kn[2][4];
            #pragma unroll
            for (int f = 0; f < 2; ++f)
                #pragma unroll
                for (int kk = 0; kk < 4; ++kk)
                    kn[f][kk] = *(const bf16x8*)&knp[f * 2048 + kk * 512];

            // causal mask: key = s0 + 32f + (r&3) + 8*(r>>2) + 4h ; q = qb + c
            if (s0 + 63 > qb) {
                #pragma unroll
                for (int f = 0; f < 2; ++f)
                    #pragma unroll
                    for (int r = 0; r < 16; ++r) {
                        const int key = s0 + f * 32 + ((r & 3) + 8 * (r >> 2)) + 4 * h;
                        if (key > qb + c) sf[f][r] = -1e30f;
                    }
            }

            // ---- online softmax (exp2 domain); 4-partial tree reductions ----
            float t0 = fmaxf(sf[0][0], sf[1][0]);
            float t1 = fmaxf(sf[0][1], sf[1][1]);
            float t2 = fmaxf(sf[0][2], sf[1][2]);
            float t3 = fmaxf(sf[0][3], sf[1][3]);
            #pragma unroll
            for (int r = 4; r < 16; r += 4) {
                t0 = fmaxf(t0, fmaxf(sf[0][r],     sf[1][r]));
                t1 = fmaxf(t1, fmaxf(sf[0][r + 1], sf[1][r + 1]));
                t2 = fmaxf(t2, fmaxf(sf[0][r + 2], sf[1][r + 2]));
                t3 = fmaxf(t3, fmaxf(sf[0][r + 3], sf[1][r + 3]));
            }
            float pm = fmaxf(fmaxf(t0, t1), fmaxf(t2, t3));
            pm = fmaxf(pm, __shfl_xor(pm, 32));

            float mn = m;
            if (__any(pm > m)) {           // exact skip: if no column grew, sc == 1
                mn = fmaxf(m, pm);
                const float sc = exp2f(m - mn);   // per-lane scalar (q = c)
                m = mn;
                l *= sc;
                #pragma unroll
                for (int ct = 0; ct < 2; ++ct)
                    #pragma unroll
                    for (int r = 0; r < 16; ++r) acc[ct][r] *= sc;
            }

            float s0a = 0.f, s1a = 0.f, s2a = 0.f, s3a = 0.f;
            #pragma unroll
            for (int f = 0; f < 2; ++f)
                #pragma unroll
                for (int r = 0; r < 16; r += 4) {
                    float p0 = exp2f(sf[f][r] - mn);
                    float p1 = exp2f(sf[f][r + 1] - mn);
                    float p2 = exp2f(sf[f][r + 2] - mn);
                    float p3 = exp2f(sf[f][r + 3] - mn);
                    sf[f][r] = p0; sf[f][r + 1] = p1; sf[f][r + 2] = p2; sf[f][r + 3] = p3;
                    s0a += p0; s1a += p1; s2a += p2; s3a += p3;
                }
            float rs = (s0a + s1a) + (s2a + s3a);
            rs += __shfl_xor(rs, 32);
            l += rs;

            // ---- P -> bf16 frags via cvt_pk + permlane32_swap; O^T += V^T P --
            #pragma unroll
            for (int f = 0; f < 2; ++f) {
                unsigned w01 = cvtpk(sf[f][0], sf[f][1]);
                unsigned w23 = cvtpk(sf[f][2], sf[f][3]);
                unsigned w45 = cvtpk(sf[f][4], sf[f][5]);
                unsigned w67 = cvtpk(sf[f][6], sf[f][7]);
                pls(w01, w45); pls(w23, w67);
                union { unsigned uu[4]; bf16x8 v; } pa0, pa1;
                pa0.uu[0] = w01; pa0.uu[1] = w23; pa0.uu[2] = w45; pa0.uu[3] = w67;
                unsigned x01 = cvtpk(sf[f][8],  sf[f][9]);
                unsigned x23 = cvtpk(sf[f][10], sf[f][11]);
                unsigned x45 = cvtpk(sf[f][12], sf[f][13]);
                unsigned x67 = cvtpk(sf[f][14], sf[f][15]);
                pls(x01, x45); pls(x23, x67);
                pa1.uu[0] = x01; pa1.uu[1] = x23; pa1.uu[2] = x45; pa1.uu[3] = x67;
                __builtin_amdgcn_s_setprio(1);
                #pragma unroll
                for (int ct = 0; ct < 2; ++ct) {
                    acc[ct] = __builtin_amdgcn_mfma_f32_32x32x16_bf16(vf[2 * f][ct],     pa0.v, acc[ct], 0, 0, 0);
                    acc[ct] = __builtin_amdgcn_mfma_f32_32x32x16_bf16(vf[2 * f + 1][ct], pa1.v, acc[ct], 0, 0, 0);
                }
                __builtin_amdgcn_s_setprio(0);
            }

            #pragma unroll
            for (int f = 0; f < 2; ++f)
                #pragma unroll
                for (int kk = 0; kk < 4; ++kk) kf[f][kk] = kn[f][kk];
            kptr += 32768;
            vptr += 32768;
        }

        // ---- split-K merge: D col = q = c, row = d = ct*32 + 8g + 4h + 0..3 --
        if (h == 0) { mbuf[w][c] = m; lbuf[w][c] = l; }
        #pragma unroll
        for (int ct = 0; ct < 2; ++ct)
            #pragma unroll
            for (int g = 0; g < 4; ++g)
                *(float4*)&accbuf[w][c][ct * 32 + g * 8 + 4 * h] =
                    make_float4(acc[ct][4 * g], acc[ct][4 * g + 1],
                                acc[ct][4 * g + 2], acc[ct][4 * g + 3]);
        __syncthreads();
        #pragma unroll
        for (int i = 0; i < 4; ++i) {
            const int e = tid + i * 512;
            const int q = e >> 6, d = e & 63;
            float ms = mbuf[0][q];
            #pragma unroll
            for (int wv = 1; wv < 8; ++wv) ms = fmaxf(ms, mbuf[wv][q]);
            float ls = 0.f, os = 0.f;
            #pragma unroll
            for (int wv = 0; wv < 8; ++wv) {
                const float e_ = exp2f(mbuf[wv][q] - ms);
                ls += lbuf[wv][q] * e_;
                os += accbuf[wv][q][d] * e_;
            }
            out[((long)b * T_ + qb + q) * 64 + d] = os / ls;
        }
        __syncthreads();   // protect accbuf/mbuf/lbuf reuse by next tile
    }
}

extern "C" void kernel_launch(void* const* d_in, const int* in_sizes, int n_in,
                              void* d_out, int out_size, void* d_ws, size_t ws_size,
                              hipStream_t stream)
{
    const float* emb = (const float*)d_in[0];
    const float* Wq  = (const float*)d_in[1];
    const float* Wk  = (const float*)d_in[2];
    const float* Wv  = (const float*)d_in[3];
    float* out = (float*)d_out;

    unsigned short* Qp = (unsigned short*)d_ws;         // 2 MB packed Q frags
    unsigned short* Kp = Qp + (size_t)B_ * T_ * A_;     // 2 MB packed K frags
    unsigned short* Vp = Kp + (size_t)B_ * T_ * A_;     // 2 MB packed V frags
    unsigned short* Wp = Vp + (size_t)B_ * T_ * A_;     // 192 KB packed W frags

    prep_w<<<dim3(48), dim3(256), 0, stream>>>(Wq, Wk, Wv, Wp);
    qkv_proj_kernel<<<dim3(512), dim3(768), 0, stream>>>(emb, Wp, Qp, Kp, Vp);
    attn_kernel<<<dim3(256), dim3(512), 0, stream>>>(Qp, Kp, Vp, out);
}